// Round 1
// baseline (3879.783 us; speedup 1.0000x reference)
//
#include <hip/hip_runtime.h>
#include <stdint.h>

#define NN 2048
#define TT 365
#define DD 16
#define HH 64
#define NBLK 128      // 16 rows per block, 1 block/CU (LDS-bound)
#define NTHR 1024     // 16 waves
#define SMEM_BYTES 150016

typedef __attribute__((ext_vector_type(8))) short bf16x8;
typedef __attribute__((ext_vector_type(4))) float f32x4;
typedef __attribute__((ext_vector_type(4))) unsigned int u32x4;

__device__ __forceinline__ unsigned short f2bf(float f) {
  union { float f; uint32_t u; } z; z.f = f;
  uint32_t r = z.u + 0x7fffu + ((z.u >> 16) & 1u);
  return (unsigned short)(r >> 16);
}
__device__ __forceinline__ float sigmoid_(float x) { return 1.f / (1.f + __expf(-x)); }
__device__ __forceinline__ float tanh_(float x) {
  float ax = fabsf(x);
  float e = __expf(-2.f * ax);
  float r = (1.f - e) / (1.f + e);
  return x < 0.f ? -r : r;
}
__device__ __forceinline__ bf16x8 asbf(u32x4 v) { return __builtin_bit_cast(bf16x8, v); }

// R14: latency-path restructure.
//  - per-wave flag wait (32 source blocks each); no fence/buffer_inv: q read
//    with sc0 sc1 (L1+L2 bypass) loads, 16 issued up-front into registers,
//    gates-GEMM + epilogue overlap the L3 latency.
//  - fused tail: q-GEMM -> tanh -> pack -> direct 8B global store -> vmcnt(0)
//    -> LDS arrival counter -> 4th wave sets flag (no sh_q, 2 fewer barriers).
//  - sh_part reduce via broadcast ds_read_b128 (kills 8-way bank conflict).
__global__ __launch_bounds__(NTHR, 4) void rgcn_persist(
    const float* __restrict__ X, const float* __restrict__ Af,
    const float* __restrict__ Wih, const float* __restrict__ Whh,
    const float* __restrict__ Bias, const float* __restrict__ Wq,
    const float* __restrict__ Bq, const float* __restrict__ Wd,
    const float* __restrict__ Bd, float* __restrict__ Out,
    uint32_t* qP0, uint32_t* qP1, uint32_t* flags)
{
  extern __shared__ __align__(16) char smem[];
  unsigned short* afrag = (unsigned short*)smem;                 // [64kc][64ln][8] 65536
  unsigned short* whxT  = (unsigned short*)(smem + 65536);       // [256n][104k]    53248
  unsigned short* wqT   = (unsigned short*)(smem + 118784);      // [64n][72k]       9216
  float*          sh_g  = (float*)(smem + 128000);               // [16][260] fp32  16640
  f32x4*          sh_part = (f32x4*)(smem + 128000);             // union (16384)
  unsigned short* sh_hx = (unsigned short*)(smem + 144640);      // [16][104] bf16   3328
  unsigned int*   cnt   = (unsigned int*)(smem + 147968);        // publish arrival ctr

  const int tid = threadIdx.x;
  const int w = tid >> 6;        // wave 0..15 (== node row for per-thread work)
  const int c = tid & 63;        // lane
  const int base = blockIdx.x * 16;
  const int m = c & 15, quad = c >> 4;
  const int nt = w & 3, kh = w >> 2;                       // phase B tile coords

  // ---- one-time staging ----
  for (int i = tid; i < 256 * 104; i += NTHR) {            // [WhhT | WihT | 0]
    int n = i / 104, k = i - n * 104;
    float v = (k < 64) ? Whh[k * 256 + n] : (k < 80) ? Wih[(k - 64) * 256 + n] : 0.f;
    whxT[i] = f2bf(v);
  }
  for (int i = tid; i < 64 * 72; i += NTHR) {              // WqT (pad k 64..71 = 0)
    int n = i / 72, k = i - n * 72;
    wqT[i] = (k < 64) ? f2bf(Wq[k * 64 + n]) : (unsigned short)0;
  }
  for (int i = tid; i < 16 * NN; i += NTHR) {              // A -> MFMA A-frag layout
    int r = i >> 11, k = i & (NN - 1);
    afrag[(k >> 5) * 512 + (((k >> 3) & 3) * 16 + r) * 8 + (k & 7)] =
        f2bf(Af[(size_t)(base + r) * NN + k]);
  }
  for (int i = tid; i < 16 * 104; i += NTHR) sh_hx[i] = 0; // h=0, x below, pad=0
  __syncthreads();
  if (c < 16) sh_hx[w * 104 + 64 + c] = f2bf(X[(size_t)(base + w) * (TT * DD) + c]);
  if (tid == 0) *cnt = 0u;
  __syncthreads();

  const float b_i = Bias[c], b_f = Bias[64 + c], b_g = Bias[128 + c], b_o = Bias[192 + c];
  const float wdc = Wd[c], bdc = Bd[0];
  const float bqv = (w < 4) ? Bq[w * 16 + m] : 0.f;        // q-GEMM col bias
  const unsigned short* afp = afrag + (kh * 16) * 512 + c * 8;

  float creg = 0.f, hreg = 0.f;

  // ---- initial publish: q_0 = tanh(b_q), identical for all 16 nodes ----
  if (w < 4) {
    unsigned short qb = f2bf(tanh_(bqv));
    uint32_t pp = (uint32_t)qb | ((uint32_t)qb << 16);
    unsigned long long v = (unsigned long long)pp | ((unsigned long long)pp << 32);
    unsigned long long* dst =
        (unsigned long long*)(qP0 + (size_t)(w * 16 + m) * (NN / 2) + (base >> 1) + 2 * quad);
    __hip_atomic_store(dst, v, __ATOMIC_RELAXED, __HIP_MEMORY_SCOPE_AGENT);
    asm volatile("s_waitcnt vmcnt(0)" ::: "memory");
    if (c == 0) {
      unsigned old = atomicAdd(cnt, 1u);
      if (old == 3u)
        __hip_atomic_store(&flags[blockIdx.x * 16], 1u,
                           __ATOMIC_RELAXED, __HIP_MEMORY_SCOPE_AGENT);
    }
  }

  for (int t = 0; t < TT; ++t) {
    // ---- per-wave wait: my 32 source blocks published q_t ----
    {
      const uint32_t target = (uint32_t)(t + 1);
      const int src = 32 * kh + (c & 31);                  // lanes 32..63 duplicate
      for (;;) {
        uint32_t f = __hip_atomic_load(&flags[src * 16],
                                       __ATOMIC_RELAXED, __HIP_MEMORY_SCOPE_AGENT);
        if (__all((int)(f >= target))) break;
        __builtin_amdgcn_s_sleep(1);
      }
    }
    __builtin_amdgcn_sched_barrier(0);

    // ---- issue all 16 q-tile loads (L1+L2 bypass -> L3; no fence needed) ----
    const unsigned short* qbase = (const unsigned short*)((t & 1) ? qP1 : qP0);
    const uint64_t qa =
        (uint64_t)(qbase + (size_t)(nt * 16 + m) * NN + kh * 512 + quad * 8);
    u32x4 qv[16];
#define QL(i, offs) asm volatile("global_load_dwordx4 %0, %1, off offset:" offs " sc0 sc1" \
                                 : "=v"(qv[i]) : "v"(qa) : "memory")
    QL(0,"0");    QL(1,"64");   QL(2,"128");  QL(3,"192");
    QL(4,"256");  QL(5,"320");  QL(6,"384");  QL(7,"448");
    QL(8,"512");  QL(9,"576");  QL(10,"640"); QL(11,"704");
    QL(12,"768"); QL(13,"832"); QL(14,"896"); QL(15,"960");
#undef QL

    float xnext = 0.f;                     // prefetch x_{t+1}
    if (c < 16 && t < TT - 1)
      xnext = X[(size_t)(base + w) * (TT * DD) + (t + 1) * DD + c];

    // ---- gates-GEMM (overlaps q-load latency) ----
    f32x4 dg = {0.f, 0.f, 0.f, 0.f};
    {
      const unsigned short* ar = sh_hx + m * 104 + quad * 8;
      const unsigned short* br = whxT + (w * 16 + m) * 104 + quad * 8;
      #pragma unroll
      for (int ch = 0; ch < 3; ++ch)
        dg = __builtin_amdgcn_mfma_f32_16x16x32_bf16(*(const bf16x8*)(ar + ch * 32),
                                                     *(const bf16x8*)(br + ch * 32), dg, 0, 0, 0);
    }
    #pragma unroll
    for (int r = 0; r < 4; ++r)            // D: row=quad*4+r, col=16w+m
      sh_g[(quad * 4 + r) * 260 + w * 16 + m] = dg[r];
    __syncthreads();                       // B1: sh_g ready

    float gi = sigmoid_(b_i + sh_g[w * 260 + c]);
    float gf = sigmoid_(b_f + sh_g[w * 260 + 64 + c]);
    float gg = tanh_  (b_g + sh_g[w * 260 + 128 + c]);
    float go = sigmoid_(b_o + sh_g[w * 260 + 192 + c]);
    __syncthreads();                       // B2: sh_g reads done before sh_part writes

    // ---- phase B: Aq_t via MFMA on prefetched registers ----
    asm volatile("s_waitcnt vmcnt(0)" ::: "memory");
    __builtin_amdgcn_sched_barrier(0);     // rule #18: pin MFMA after the wait
    f32x4 acc0 = {0.f,0.f,0.f,0.f}, acc1 = {0.f,0.f,0.f,0.f};
    #pragma unroll
    for (int ch = 0; ch < 16; ch += 2) {   // dual chain halves dep depth
      acc0 = __builtin_amdgcn_mfma_f32_16x16x32_bf16(
          *(const bf16x8*)(afp + ch * 512), asbf(qv[ch]), acc0, 0, 0, 0);
      acc1 = __builtin_amdgcn_mfma_f32_16x16x32_bf16(
          *(const bf16x8*)(afp + (ch + 1) * 512), asbf(qv[ch + 1]), acc1, 0, 0, 0);
    }
    sh_part[w * 64 + c] = acc0 + acc1;
    __syncthreads();                       // B3

    // conflict-free reduce: broadcast b128 reads, vector sum, uniform select
    f32x4 vs;
    {
      const f32x4* sp = sh_part;
      const int li = (w >> 2) * 16 + m;
      f32x4 p0 = sp[(0 * 4 + quad) * 64 + li];
      f32x4 p1 = sp[(1 * 4 + quad) * 64 + li];
      f32x4 p2 = sp[(2 * 4 + quad) * 64 + li];
      f32x4 p3 = sp[(3 * 4 + quad) * 64 + li];
      vs = (p0 + p1) + (p2 + p3);
    }
    float a01 = (w & 1) ? vs[1] : vs[0];
    float a23 = (w & 1) ? vs[3] : vs[2];
    float aqv = (w & 2) ? a23 : a01;

    // ---- update ----
    creg = gf * (creg + aqv) + gi * gg;
    hreg = go * tanh_(creg);
    sh_hx[w * 104 + c] = f2bf(hreg);
    if (c < 16) sh_hx[w * 104 + 64 + c] = f2bf(xnext);
    __syncthreads();                       // B4: h_t visible

    // ---- fused q-GEMM + register publish (waves 0..3) ----
    if (w < 4 && t < TT - 1) {
      f32x4 dq = {0.f, 0.f, 0.f, 0.f};
      const unsigned short* ar = sh_hx + m * 104 + quad * 8;
      const unsigned short* br = wqT + (w * 16 + m) * 72 + quad * 8;
      #pragma unroll
      for (int k2 = 0; k2 < 2; ++k2)
        dq = __builtin_amdgcn_mfma_f32_16x16x32_bf16(*(const bf16x8*)(ar + k2 * 32),
                                                     *(const bf16x8*)(br + k2 * 32), dq, 0, 0, 0);
      // D: row=quad*4+r (node), col=16w+m -> 4 consecutive nodes = one 8B store
      unsigned short b0 = f2bf(tanh_(dq[0] + bqv));
      unsigned short b1 = f2bf(tanh_(dq[1] + bqv));
      unsigned short b2 = f2bf(tanh_(dq[2] + bqv));
      unsigned short b3 = f2bf(tanh_(dq[3] + bqv));
      unsigned long long v =
          (unsigned long long)((uint32_t)b0 | ((uint32_t)b1 << 16)) |
          ((unsigned long long)((uint32_t)b2 | ((uint32_t)b3 << 16)) << 32);
      uint32_t* qPn = (t & 1) ? qP0 : qP1;
      unsigned long long* dst =
          (unsigned long long*)(qPn + (size_t)(w * 16 + m) * (NN / 2) + (base >> 1) + 2 * quad);
      __hip_atomic_store(dst, v, __ATOMIC_RELAXED, __HIP_MEMORY_SCOPE_AGENT);
      asm volatile("s_waitcnt vmcnt(0)" ::: "memory");     // q acked at L3
      if (c == 0) {
        unsigned old = atomicAdd(cnt, 1u);                 // LDS arrival counter
        if (old == (unsigned)(4 * t + 7))                  // 4th wave of this step
          __hip_atomic_store(&flags[blockIdx.x * 16], (uint32_t)(t + 2),
                             __ATOMIC_RELAXED, __HIP_MEMORY_SCOPE_AGENT);
      }
    }

    // ---- output projection (off the publish critical path) ----
    float red = hreg * wdc;
    #pragma unroll
    for (int off = 32; off; off >>= 1) red += __shfl_xor(red, off);
    if (c == 0) {
      union { float f; uint32_t u; } o; o.f = red + bdc;
      __hip_atomic_store((uint32_t*)&Out[(size_t)(base + w) * TT + t], o.u,
                         __ATOMIC_RELAXED, __HIP_MEMORY_SCOPE_AGENT);
    }
  }
}

extern "C" void kernel_launch(void* const* d_in, const int* in_sizes, int n_in,
                              void* d_out, int out_size, void* d_ws, size_t ws_size,
                              hipStream_t stream) {
  const float* X    = (const float*)d_in[0];
  const float* Af   = (const float*)d_in[1];
  const float* Wih  = (const float*)d_in[2];
  const float* Whh  = (const float*)d_in[3];
  const float* Bias = (const float*)d_in[4];
  const float* Wq   = (const float*)d_in[5];
  const float* Bq   = (const float*)d_in[6];
  const float* Wd   = (const float*)d_in[7];
  const float* Bd   = (const float*)d_in[8];
  float* Out = (float*)d_out;

  char* ws = (char*)d_ws;
  uint32_t* flags = (uint32_t*)ws;                         // 128 flags, 64B apart (8 KB)
  uint32_t* qP0   = (uint32_t*)(ws + 8192);                // 64*1024 u32 = 256 KB
  uint32_t* qP1   = (uint32_t*)(ws + 8192 + 262144);       // 256 KB

  hipFuncSetAttribute((const void*)rgcn_persist,
                      hipFuncAttributeMaxDynamicSharedMemorySize, SMEM_BYTES);
  hipMemsetAsync(ws, 0, 8192, stream);                     // zero flags (poisoned 0xAA!)
  hipLaunchKernelGGL(rgcn_persist, dim3(NBLK), dim3(NTHR), SMEM_BYTES, stream,
                     X, Af, Wih, Whh, Bias, Wq, Bq, Wd, Bd, Out, qP0, qP1, flags);
}

// Round 2
// 3769.103 us; speedup vs baseline: 1.0294x; 1.0294x over previous
//
#include <hip/hip_runtime.h>
#include <stdint.h>

#define NN 2048
#define TT 365
#define DD 16
#define HH 64
#define NBLK 128      // 16 rows per block, 1 block/CU (LDS-bound)
#define NTHR 1024     // 16 waves
#define SMEM_BYTES 150016
#define QSLOT_U32 65536          // 64 cols x 2048 nodes bf16 = 256 KB per ring slot

typedef __attribute__((ext_vector_type(8))) short bf16x8;
typedef __attribute__((ext_vector_type(4))) float f32x4;

__device__ __forceinline__ unsigned short f2bf(float f) {
  union { float f; uint32_t u; } z; z.f = f;
  uint32_t r = z.u + 0x7fffu + ((z.u >> 16) & 1u);
  return (unsigned short)(r >> 16);
}
__device__ __forceinline__ float sigmoid_(float x) { return 1.f / (1.f + __expf(-x)); }
__device__ __forceinline__ float tanh_(float x) {
  float ax = fabsf(x);
  float e = __expf(-2.f * ax);
  float r = (1.f - e) / (1.f + e);
  return x < 0.f ? -r : r;
}

// R15: q exchanged through a per-step RING (fresh address each step) so
// consumer reads are plain L2-cached loads: 16 blocks/XCD share one L3 fetch
// of each q line (32 MB/step -> 2 MB/step of L3 traffic). No buffer_inv, no
// sc0sc1 bypass on the consumer side. Publishers still write through to L3
// (sc1 agent stores) + vmcnt(0) + flag. amdgpu_waves_per_eu(4,4) forces the
// 128-VGPR budget so the 16-chunk q prefetch stays in registers (R14 spilled
// at the compiler's default 64-VGPR/8-wave heuristic).
// Fallback (ws too small for 366 slots): short ring + per-step acquire fence.
__global__ __launch_bounds__(NTHR) __attribute__((amdgpu_waves_per_eu(4, 4)))
void rgcn_persist(
    const float* __restrict__ X, const float* __restrict__ Af,
    const float* __restrict__ Wih, const float* __restrict__ Whh,
    const float* __restrict__ Bias, const float* __restrict__ Wq,
    const float* __restrict__ Bq, const float* __restrict__ Wd,
    const float* __restrict__ Bd, float* __restrict__ Out,
    uint32_t* qRing, uint32_t* flags, int rdepth, int ringfull)
{
  extern __shared__ __align__(16) char smem[];
  unsigned short* afrag = (unsigned short*)smem;                 // [64kc][64ln][8] 65536
  unsigned short* whxT  = (unsigned short*)(smem + 65536);       // [256n][104k]    53248
  unsigned short* wqT   = (unsigned short*)(smem + 118784);      // [64n][72k]       9216
  float*          sh_g  = (float*)(smem + 128000);               // [16][260] fp32  16640
  f32x4*          sh_part = (f32x4*)(smem + 128000);             // union (16384)
  unsigned short* sh_hx = (unsigned short*)(smem + 144640);      // [16][104] bf16   3328
  unsigned int*   cnt   = (unsigned int*)(smem + 147968);        // publish arrival ctr

  const int tid = threadIdx.x;
  const int w = tid >> 6;        // wave 0..15 (== node row for per-thread work)
  const int c = tid & 63;        // lane
  const int base = blockIdx.x * 16;
  const int m = c & 15, quad = c >> 4;
  const int nt = w & 3, kh = w >> 2;                       // phase B tile coords

  // ---- one-time staging ----
  for (int i = tid; i < 256 * 104; i += NTHR) {            // [WhhT | WihT | 0]
    int n = i / 104, k = i - n * 104;
    float v = (k < 64) ? Whh[k * 256 + n] : (k < 80) ? Wih[(k - 64) * 256 + n] : 0.f;
    whxT[i] = f2bf(v);
  }
  for (int i = tid; i < 64 * 72; i += NTHR) {              // WqT (pad k 64..71 = 0)
    int n = i / 72, k = i - n * 72;
    wqT[i] = (k < 64) ? f2bf(Wq[k * 64 + n]) : (unsigned short)0;
  }
  for (int i = tid; i < 16 * NN; i += NTHR) {              // A -> MFMA A-frag layout
    int r = i >> 11, k = i & (NN - 1);
    afrag[(k >> 5) * 512 + (((k >> 3) & 3) * 16 + r) * 8 + (k & 7)] =
        f2bf(Af[(size_t)(base + r) * NN + k]);
  }
  for (int i = tid; i < 16 * 104; i += NTHR) sh_hx[i] = 0; // h=0, x below, pad=0
  __syncthreads();
  if (c < 16) sh_hx[w * 104 + 64 + c] = f2bf(X[(size_t)(base + w) * (TT * DD) + c]);
  if (tid == 0) *cnt = 0u;
  __syncthreads();

  const float b_i = Bias[c], b_f = Bias[64 + c], b_g = Bias[128 + c], b_o = Bias[192 + c];
  const float wdc = Wd[c], bdc = Bd[0];
  const float bqv = (w < 4) ? Bq[w * 16 + m] : 0.f;        // q-GEMM col bias
  const unsigned short* afp = afrag + (kh * 16) * 512 + c * 8;

  float creg = 0.f, hreg = 0.f;

  // ---- initial publish: q_0 = tanh(b_q) -> ring slot 0 ----
  if (w < 4) {
    unsigned short qb = f2bf(tanh_(bqv));
    uint32_t pp = (uint32_t)qb | ((uint32_t)qb << 16);
    unsigned long long v = (unsigned long long)pp | ((unsigned long long)pp << 32);
    unsigned long long* dst =
        (unsigned long long*)(qRing + (size_t)(w * 16 + m) * (NN / 2) + (base >> 1) + 2 * quad);
    __hip_atomic_store(dst, v, __ATOMIC_RELAXED, __HIP_MEMORY_SCOPE_AGENT);
    asm volatile("s_waitcnt vmcnt(0)" ::: "memory");
    if (c == 0) {
      unsigned old = atomicAdd(cnt, 1u);
      if (old == 3u)
        __hip_atomic_store(&flags[blockIdx.x * 16], 1u,
                           __ATOMIC_RELAXED, __HIP_MEMORY_SCOPE_AGENT);
    }
  }

  int slotR = 0;                                           // read slot = t % rdepth
  for (int t = 0; t < TT; ++t) {
    const int slotW = (slotR + 1 == rdepth) ? 0 : slotR + 1;

    // ---- per-wave wait: my 32 source blocks published q_t ----
    {
      const uint32_t target = (uint32_t)(t + 1);
      const int src = 32 * kh + (c & 31);                  // lanes 32..63 duplicate
      for (;;) {
        uint32_t f = __hip_atomic_load(&flags[src * 16],
                                       __ATOMIC_RELAXED, __HIP_MEMORY_SCOPE_AGENT);
        if (__all((int)(f >= target))) break;
        __builtin_amdgcn_s_sleep(1);
      }
    }
    asm volatile("" ::: "memory");
    __builtin_amdgcn_sched_barrier(0);
    if (!ringfull)                                         // slot reuse -> inv stale L2
      __builtin_amdgcn_fence(__ATOMIC_ACQUIRE, "agent");

    // ---- q prefetch: plain cached loads (L2-shared across the XCD) ----
    const unsigned short* qslot = (const unsigned short*)(qRing + (size_t)slotR * QSLOT_U32);
    const unsigned short* qrow = qslot + (size_t)(nt * 16 + m) * NN + kh * 512 + quad * 8;
    bf16x8 qv[16];
    #pragma unroll
    for (int ch = 0; ch < 16; ++ch)
      qv[ch] = *(const bf16x8*)(qrow + ch * 32);

    float xnext = 0.f;                     // prefetch x_{t+1}
    if (c < 16 && t < TT - 1)
      xnext = X[(size_t)(base + w) * (TT * DD) + (t + 1) * DD + c];

    // ---- gates-GEMM (overlaps q-load latency) ----
    f32x4 dg = {0.f, 0.f, 0.f, 0.f};
    {
      const unsigned short* ar = sh_hx + m * 104 + quad * 8;
      const unsigned short* br = whxT + (w * 16 + m) * 104 + quad * 8;
      #pragma unroll
      for (int ch = 0; ch < 3; ++ch)
        dg = __builtin_amdgcn_mfma_f32_16x16x32_bf16(*(const bf16x8*)(ar + ch * 32),
                                                     *(const bf16x8*)(br + ch * 32), dg, 0, 0, 0);
    }
    #pragma unroll
    for (int r = 0; r < 4; ++r)            // D: row=quad*4+r, col=16w+m
      sh_g[(quad * 4 + r) * 260 + w * 16 + m] = dg[r];
    __syncthreads();                       // B1: sh_g ready

    float gi = sigmoid_(b_i + sh_g[w * 260 + c]);
    float gf = sigmoid_(b_f + sh_g[w * 260 + 64 + c]);
    float gg = tanh_  (b_g + sh_g[w * 260 + 128 + c]);
    float go = sigmoid_(b_o + sh_g[w * 260 + 192 + c]);
    __syncthreads();                       // B2: sh_g reads done before sh_part writes

    // ---- phase B: Aq_t via MFMA on prefetched registers ----
    f32x4 acc0 = {0.f,0.f,0.f,0.f}, acc1 = {0.f,0.f,0.f,0.f};
    #pragma unroll
    for (int ch = 0; ch < 16; ch += 2) {   // dual chain halves dep depth
      acc0 = __builtin_amdgcn_mfma_f32_16x16x32_bf16(
          *(const bf16x8*)(afp + ch * 512), qv[ch], acc0, 0, 0, 0);
      acc1 = __builtin_amdgcn_mfma_f32_16x16x32_bf16(
          *(const bf16x8*)(afp + (ch + 1) * 512), qv[ch + 1], acc1, 0, 0, 0);
    }
    sh_part[w * 64 + c] = acc0 + acc1;
    __syncthreads();                       // B3

    // conflict-free reduce: broadcast b128 reads, vector sum, uniform select
    f32x4 vs;
    {
      const f32x4* sp = sh_part;
      const int li = (w >> 2) * 16 + m;
      f32x4 p0 = sp[(0 * 4 + quad) * 64 + li];
      f32x4 p1 = sp[(1 * 4 + quad) * 64 + li];
      f32x4 p2 = sp[(2 * 4 + quad) * 64 + li];
      f32x4 p3 = sp[(3 * 4 + quad) * 64 + li];
      vs = (p0 + p1) + (p2 + p3);
    }
    float a01 = (w & 1) ? vs[1] : vs[0];
    float a23 = (w & 1) ? vs[3] : vs[2];
    float aqv = (w & 2) ? a23 : a01;

    // ---- update ----
    creg = gf * (creg + aqv) + gi * gg;
    hreg = go * tanh_(creg);
    sh_hx[w * 104 + c] = f2bf(hreg);
    if (c < 16) sh_hx[w * 104 + 64 + c] = f2bf(xnext);
    __syncthreads();                       // B4: h_t visible

    // ---- fused q-GEMM + register publish into ring slot (t+1)%R ----
    if (w < 4 && t < TT - 1) {
      f32x4 dq = {0.f, 0.f, 0.f, 0.f};
      const unsigned short* ar = sh_hx + m * 104 + quad * 8;
      const unsigned short* br = wqT + (w * 16 + m) * 72 + quad * 8;
      #pragma unroll
      for (int k2 = 0; k2 < 2; ++k2)
        dq = __builtin_amdgcn_mfma_f32_16x16x32_bf16(*(const bf16x8*)(ar + k2 * 32),
                                                     *(const bf16x8*)(br + k2 * 32), dq, 0, 0, 0);
      // D: row=quad*4+r (node), col=16w+m -> 4 consecutive nodes = one 8B store
      unsigned short b0 = f2bf(tanh_(dq[0] + bqv));
      unsigned short b1 = f2bf(tanh_(dq[1] + bqv));
      unsigned short b2 = f2bf(tanh_(dq[2] + bqv));
      unsigned short b3 = f2bf(tanh_(dq[3] + bqv));
      unsigned long long v =
          (unsigned long long)((uint32_t)b0 | ((uint32_t)b1 << 16)) |
          ((unsigned long long)((uint32_t)b2 | ((uint32_t)b3 << 16)) << 32);
      unsigned long long* dst =
          (unsigned long long*)(qRing + (size_t)slotW * QSLOT_U32 +
                                (size_t)(w * 16 + m) * (NN / 2) + (base >> 1) + 2 * quad);
      __hip_atomic_store(dst, v, __ATOMIC_RELAXED, __HIP_MEMORY_SCOPE_AGENT);
      asm volatile("s_waitcnt vmcnt(0)" ::: "memory");     // q acked at coherence point
      if (c == 0) {
        unsigned old = atomicAdd(cnt, 1u);                 // LDS arrival counter
        if (old == (unsigned)(4 * t + 7))                  // 4th wave of this step
          __hip_atomic_store(&flags[blockIdx.x * 16], (uint32_t)(t + 2),
                             __ATOMIC_RELAXED, __HIP_MEMORY_SCOPE_AGENT);
      }
    }

    // ---- output projection (off the publish critical path) ----
    float red = hreg * wdc;
    #pragma unroll
    for (int off = 32; off; off >>= 1) red += __shfl_xor(red, off);
    if (c == 0) {
      union { float f; uint32_t u; } o; o.f = red + bdc;
      __hip_atomic_store((uint32_t*)&Out[(size_t)(base + w) * TT + t], o.u,
                         __ATOMIC_RELAXED, __HIP_MEMORY_SCOPE_AGENT);
    }

    slotR = slotW;
  }
}

extern "C" void kernel_launch(void* const* d_in, const int* in_sizes, int n_in,
                              void* d_out, int out_size, void* d_ws, size_t ws_size,
                              hipStream_t stream) {
  const float* X    = (const float*)d_in[0];
  const float* Af   = (const float*)d_in[1];
  const float* Wih  = (const float*)d_in[2];
  const float* Whh  = (const float*)d_in[3];
  const float* Bias = (const float*)d_in[4];
  const float* Wq   = (const float*)d_in[5];
  const float* Bq   = (const float*)d_in[6];
  const float* Wd   = (const float*)d_in[7];
  const float* Bd   = (const float*)d_in[8];
  float* Out = (float*)d_out;

  char* ws = (char*)d_ws;
  uint32_t* flags = (uint32_t*)ws;                         // 128 flags, 64B apart (8 KB)
  uint32_t* qRing = (uint32_t*)(ws + 8192);                // R slots x 256 KB

  // ring depth: one fresh slot per step if workspace allows (TT+1 = 366 slots
  // = 94 MB -> every consumer read is L2-cacheable with no invalidation).
  long long avail = (long long)ws_size - 8192;
  int rdepth = (int)(avail / (QSLOT_U32 * 4));
  if (rdepth > TT + 1) rdepth = TT + 1;
  if (rdepth < 2) rdepth = 2;                              // safety (ws >= 528 KB known)
  int ringfull = (rdepth >= TT + 1) ? 1 : 0;

  hipFuncSetAttribute((const void*)rgcn_persist,
                      hipFuncAttributeMaxDynamicSharedMemorySize, SMEM_BYTES);
  hipMemsetAsync(ws, 0, 8192, stream);                     // zero flags (poisoned 0xAA!)
  hipLaunchKernelGGL(rgcn_persist, dim3(NBLK), dim3(NTHR), SMEM_BYTES, stream,
                     X, Af, Wih, Whh, Bias, Wq, Bq, Wd, Bd, Out, qRing, flags,
                     rdepth, ringfull);
}